// Round 25
// baseline (124.128 us; speedup 1.0000x reference)
//
#include <hip/hip_runtime.h>
#include <hip/hip_bf16.h>
#include <math.h>

typedef __bf16 bf16;
typedef __bf16 bf16x4 __attribute__((ext_vector_type(4)));
typedef __bf16 bf16x8 __attribute__((ext_vector_type(8)));
typedef float f32x4 __attribute__((ext_vector_type(4)));
typedef unsigned int uint32x4 __attribute__((ext_vector_type(4)));

#define AS1 __attribute__((address_space(1)))
#define AS3 __attribute__((address_space(3)))

__device__ __forceinline__ void gload_lds16(const void* g, void* l) {
  __builtin_amdgcn_global_load_lds((const AS1 void*)g, (AS3 void*)l, 16, 0, 0);
}

__device__ __forceinline__ unsigned packbf16(float a, float b) {
  bf16 x = (bf16)a, y = (bf16)b;
  unsigned short ux, uy;
  __builtin_memcpy(&ux, &x, 2);
  __builtin_memcpy(&uy, &y, 2);
  return (unsigned)ux | ((unsigned)uy << 16);
}

// ---------------- weight transpose: W[k][c] f32 -> Wt[c][k] bf16 ----------------
__global__ __launch_bounds__(256) void transpose_w_kernel(
    const float* __restrict__ wq, const float* __restrict__ wk,
    const float* __restrict__ wv, const float* __restrict__ wo,
    bf16* __restrict__ wqkv_t, bf16* __restrict__ wo_t) {
  __shared__ float t[64 * 65];
  int ct = blockIdx.x & 31, kt = blockIdx.x >> 5;
  int p = ct >> 3;                       // 0=wq 1=wk 2=wv 3=wo
  const float* src = (p == 0) ? wq : (p == 1) ? wk : (p == 2) ? wv : wo;
  int c0 = (ct & 7) * 64;
  int k0 = kt * 64;
  int tid = threadIdx.x;
  for (int i = 0; i < 16; ++i) {
    int idx = i * 256 + tid;
    int r = idx >> 6, c = idx & 63;
    t[r * 65 + c] = src[(size_t)(k0 + r) * 512 + c0 + c];
  }
  __syncthreads();
  for (int i = 0; i < 16; ++i) {
    int idx = i * 256 + tid;
    int cc = idx >> 6, kk = idx & 63;
    float v = t[kk * 65 + cc];
    int col = c0 + cc;
    if (p < 3) wqkv_t[(size_t)(p * 512 + col) * 512 + k0 + kk] = (bf16)v;
    else       wo_t[(size_t)col * 512 + k0 + kk] = (bf16)v;
  }
}

// ---------------- QKV GEMM with fused f32->bf16 cvt of x (A reg-staged) ----------------
// BM=64, BN=128; Q scaled by 0.125*log2(e) in epilogue.
__global__ __launch_bounds__(256) void gemm_qkv_kernel(
    const float* __restrict__ x, const bf16* __restrict__ Bt,
    bf16* __restrict__ qw, bf16* __restrict__ kw, bf16* __restrict__ vtw) {
  __shared__ bf16 ldsA[64 * 64];
  __shared__ bf16 ldsB[128 * 64];
  int tid = threadIdx.x;
  int wave = tid >> 6, l = tid & 63;
  int lr = l & 15, lg = l >> 4;
  int bm = blockIdx.x & 63, bn = blockIdx.x >> 6;
  int wr = wave >> 1, wc = wave & 1;

  f32x4 acc[2][4] = {};

  for (int k0 = 0; k0 < 512; k0 += 64) {
    #pragma unroll
    for (int i = 0; i < 4; ++i) {
      int off = i * 4096 + tid * 16;
      int r = off >> 7, cb = off & 127;
      gload_lds16((const char*)(Bt + (size_t)(bn * 128 + r) * 512 + k0) + cb,
                  (char*)ldsB + i * 4096 + wave * 1024);
    }
    #pragma unroll
    for (int c = 0; c < 4; ++c) {
      int idx = c * 256 + tid;            // 0..1023 float4-slots
      int r = idx >> 4, f4 = idx & 15;
      float4 v = *(const float4*)(x + (size_t)(bm * 64 + r) * 512 + k0 + f4 * 4);
      bf16x4 o;
      o[0] = (bf16)v.x; o[1] = (bf16)v.y; o[2] = (bf16)v.z; o[3] = (bf16)v.w;
      *(bf16x4*)(ldsA + r * 64 + f4 * 4) = o;
    }
    __syncthreads();
    #pragma unroll
    for (int ks = 0; ks < 2; ++ks) {
      bf16x8 af[2], bfr[4];
      #pragma unroll
      for (int m = 0; m < 2; ++m)
        af[m] = *(const bf16x8*)(ldsA + (wr * 32 + m * 16 + lr) * 64 + ks * 32 + lg * 8);
      #pragma unroll
      for (int n = 0; n < 4; ++n)
        bfr[n] = *(const bf16x8*)(ldsB + (wc * 64 + n * 16 + lr) * 64 + ks * 32 + lg * 8);
      #pragma unroll
      for (int m = 0; m < 2; ++m)
        #pragma unroll
        for (int n = 0; n < 4; ++n)
          acc[m][n] = __builtin_amdgcn_mfma_f32_16x16x32_bf16(af[m], bfr[n], acc[m][n], 0, 0, 0);
    }
    __syncthreads();
  }

  #pragma unroll
  for (int m = 0; m < 2; ++m)
    #pragma unroll
    for (int n = 0; n < 4; ++n)
      #pragma unroll
      for (int j = 0; j < 4; ++j) {
        float v = acc[m][n][j];
        int row = bm * 64 + wr * 32 + m * 16 + lg * 4 + j;
        int col = bn * 128 + wc * 64 + n * 16 + lr;
        int part = col >> 9, cp = col & 511;
        int h = cp >> 6, d = cp & 63;
        int b = row >> 11, lq = row & 2047;
        size_t bh = (size_t)(b * 8 + h);
        if (part == 0)      qw[(bh * 2048 + lq) * 64 + d] = (bf16)(v * 0.18033688f);
        else if (part == 1) kw[(bh * 2048 + lq) * 64 + d] = (bf16)v;
        else                vtw[(bh * 64 + d) * 2048 + lq] = (bf16)v;
      }
}

// ---------------- output GEMM: C[M][N] = A[M][K] * Bt[N][K]^T, f32 out ----------------
__global__ __launch_bounds__(256) void gemm_out_kernel(
    const bf16* __restrict__ A, const bf16* __restrict__ Bt,
    float* __restrict__ Cf, int M, int N, int K) {
  __shared__ bf16 ldsA[64 * 64];
  __shared__ bf16 ldsB[64 * 64];
  int tid = threadIdx.x;
  int wave = tid >> 6, l = tid & 63;
  int lr = l & 15, lg = l >> 4;
  int nbm = M >> 6;
  int bm = blockIdx.x % nbm, bn = blockIdx.x / nbm;
  int wr = wave >> 1, wc = wave & 1;

  f32x4 acc[2][2] = {};

  for (int k0 = 0; k0 < K; k0 += 64) {
    #pragma unroll
    for (int i = 0; i < 2; ++i) {
      int off = i * 4096 + tid * 16;
      int r = off >> 7, cb = off & 127;
      gload_lds16((const char*)(A + (size_t)(bm * 64 + r) * K + k0) + cb,
                  (char*)ldsA + i * 4096 + wave * 1024);
      gload_lds16((const char*)(Bt + (size_t)(bn * 64 + r) * K + k0) + cb,
                  (char*)ldsB + i * 4096 + wave * 1024);
    }
    __syncthreads();
    #pragma unroll
    for (int ks = 0; ks < 2; ++ks) {
      bf16x8 af[2], bfr[2];
      #pragma unroll
      for (int m = 0; m < 2; ++m)
        af[m] = *(const bf16x8*)(ldsA + (wr * 32 + m * 16 + lr) * 64 + ks * 32 + lg * 8);
      #pragma unroll
      for (int n = 0; n < 2; ++n)
        bfr[n] = *(const bf16x8*)(ldsB + (wc * 32 + n * 16 + lr) * 64 + ks * 32 + lg * 8);
      #pragma unroll
      for (int m = 0; m < 2; ++m)
        #pragma unroll
        for (int n = 0; n < 2; ++n)
          acc[m][n] = __builtin_amdgcn_mfma_f32_16x16x32_bf16(af[m], bfr[n], acc[m][n], 0, 0, 0);
    }
    __syncthreads();
  }

  #pragma unroll
  for (int m = 0; m < 2; ++m)
    #pragma unroll
    for (int n = 0; n < 2; ++n)
      #pragma unroll
      for (int j = 0; j < 4; ++j) {
        int row = bm * 64 + wr * 32 + m * 16 + lg * 4 + j;
        int col = bn * 64 + wc * 32 + n * 16 + lr;
        Cf[(size_t)row * N + col] = acc[m][n][j];
      }
}

// ---------------- attention: kv-split x8, launch_bounds(512,4), vmcnt(2) pipeline ----------------
// r23 structure (correctness-proven) with the ONE fatal knob fixed: launch_bounds
// stays (512,4) -> VGPR cap 128, compiler picks ~64, NO spill. Actual footprint
// (64 VGPR, 32 KB LDS) lets HW co-schedule 4 blocks/CU = 32 waves/CU with grid
// 1024 (4 KV tiles per block). r23's (512,8) capped VGPR at 32 -> 780 MB spill.
__global__ __launch_bounds__(512, 4) void attn_kernel(
    const bf16* __restrict__ qw, const bf16* __restrict__ kw,
    const bf16* __restrict__ vtw,
    bf16* __restrict__ pOb, float* __restrict__ pLb) {
  __shared__ bf16 ldsK[2][64 * 64];
  __shared__ bf16 ldsV[2][64 * 64];   // [d][s] layout (V^T tile)

  // bijective XCD swizzle: 1024 blocks -> each XCD gets 128 consecutive = 2 bh
  int swzb = ((blockIdx.x & 7) << 7) | (blockIdx.x >> 3);
  int bh = swzb >> 6, qblk = (swzb >> 3) & 7, kv = swzb & 7;

  int tid = threadIdx.x, wave = tid >> 6, l = tid & 63;
  int lr = l & 15, lg = l >> 4;
  const bf16* Q  = qw  + (size_t)bh * 2048 * 64;
  const bf16* Kp = kw  + (size_t)bh * 2048 * 64;
  const bf16* Vt = vtw + (size_t)bh * 64 * 2048;
  int qbase = qblk * 256 + wave * 32;
  int td = qblk * 4 + (wave >> 1);     // k-tile containing this wave's diagonal
  int qoff = (wave & 1) * 32;          // wave's offset within tile td

  // Q fragments (pre-scaled by 0.125*log2e in QKV epilogue): 2 subtiles x 2 ks
  bf16x8 qf[2][2];
  #pragma unroll
  for (int s = 0; s < 2; ++s)
    #pragma unroll
    for (int ks = 0; ks < 2; ++ks)
      qf[s][ks] = *(const bf16x8*)(Q + (size_t)(qbase + s * 16 + lr) * 64 + ks * 32 + lg * 8);

  // staging: 512 threads cover one 64x128B tile per gload; SWZ(r)=((r&3)|((r>>3&1)<<2))<<4
  int rowT = tid >> 3;
  int colT = (tid & 7) * 16;
  int swc = colT ^ ((((rowT & 3) | (((rowT >> 3) & 1) << 2))) << 4);

  // read-side xor constants (SWZ of the row being read; n-independent)
  int kxor = (((lr & 3) | (((lr >> 2) & 1) << 2)) << 4);
  int vxor = (((lr & 3) | (((lr >> 3) & 1) << 2)) << 4);

  f32x4 acc[2][4] = {};
  float lsum[2] = {0.f, 0.f};

  auto stage = [&](int buf, int t) {
    gload_lds16((const char*)Kp + (size_t)t * 8192 + rowT * 128 + swc,
                (char*)ldsK[buf] + wave * 1024);
    gload_lds16((const char*)Vt + (size_t)t * 128 + (size_t)rowT * 4096 + swc,
                (char*)ldsV[buf] + wave * 1024);
  };

  int t0 = kv * 4;
  stage(0, t0);

  for (int tt = 0; tt < 4; ++tt) {
    int t = t0 + tt;
    int buf = tt & 1;
    if (tt < 3) {
      stage(buf ^ 1, t + 1);                           // next tile stays in flight
      asm volatile("s_waitcnt vmcnt(2)" ::: "memory"); // current-buf loads done
    } else {
      asm volatile("s_waitcnt vmcnt(0)" ::: "memory");
    }
    __builtin_amdgcn_s_barrier();
    __builtin_amdgcn_sched_barrier(0);

    // swapped QK^T with remapped K-rows: ps[s][n] lane(lr,lg) reg j =
    //   P[k=(n>>1)*32+lg*8+(n&1)*4+j][q=qbase+s*16+lr]
    f32x4 ps[2][4] = {};
    __builtin_amdgcn_s_setprio(1);
    #pragma unroll
    for (int ks = 0; ks < 2; ++ks)
      #pragma unroll
      for (int n = 0; n < 4; ++n) {
        int mrow = ((n >> 1) << 5) + ((lr >> 2) << 3) + ((n & 1) << 2) + (lr & 3);
        bf16x8 kf = *(const bf16x8*)((const char*)ldsK[buf] + mrow * 128 +
                                     ((ks * 64 + lg * 16) ^ kxor));
        #pragma unroll
        for (int s = 0; s < 2; ++s)
          ps[s][n] = __builtin_amdgcn_mfma_f32_16x16x32_bf16(kf, qf[s][ks], ps[s][n], 0, 0, 0);
      }
    __builtin_amdgcn_s_setprio(0);

    // diagonal mask: k_local == q_local within this wave's diagonal tile
    if (t == td) {
      #pragma unroll
      for (int s = 0; s < 2; ++s)
        #pragma unroll
        for (int n = 0; n < 4; ++n)
          #pragma unroll
          for (int j = 0; j < 4; ++j)
            if (((n >> 1) * 32 + lg * 8 + (n & 1) * 4 + j) == qoff + s * 16 + lr)
              ps[s][n][j] = -INFINITY;
    }

    // fixed-max softmax (bare v_exp_f32) + in-register P->bf16 A-fragment assembly
    bf16x8 pf[2][2];
    #pragma unroll
    for (int s = 0; s < 2; ++s) {
      unsigned u[4][2];
      #pragma unroll
      for (int n = 0; n < 4; ++n) {
        float p0 = __builtin_amdgcn_exp2f(ps[s][n][0]);
        float p1 = __builtin_amdgcn_exp2f(ps[s][n][1]);
        float p2 = __builtin_amdgcn_exp2f(ps[s][n][2]);
        float p3 = __builtin_amdgcn_exp2f(ps[s][n][3]);
        lsum[s] += (p0 + p1) + (p2 + p3);
        u[n][0] = packbf16(p0, p1);
        u[n][1] = packbf16(p2, p3);
      }
      uint32x4 w0 = {u[0][0], u[0][1], u[1][0], u[1][1]};
      uint32x4 w1 = {u[2][0], u[2][1], u[3][0], u[3][1]};
      pf[s][0] = __builtin_bit_cast(bf16x8, w0);
      pf[s][1] = __builtin_bit_cast(bf16x8, w1);
    }

    // O += P V : vf shared across both subtiles
    __builtin_amdgcn_s_setprio(1);
    #pragma unroll
    for (int ks = 0; ks < 2; ++ks)
      #pragma unroll
      for (int n = 0; n < 4; ++n) {
        int vrow = n * 16 + lr;
        bf16x8 vf = *(const bf16x8*)((const char*)ldsV[buf] + vrow * 128 +
                                     ((ks * 64 + lg * 16) ^ vxor));
        #pragma unroll
        for (int s = 0; s < 2; ++s)
          acc[s][n] = __builtin_amdgcn_mfma_f32_16x16x32_bf16(pf[s][ks], vf, acc[s][n], 0, 0, 0);
      }
    __builtin_amdgcn_s_setprio(0);
    __builtin_amdgcn_s_barrier();          // release buf before next iter's stage
  }

  // lsum: reduce across the 4 lg-groups sharing the same q (=lr)
  #pragma unroll
  for (int s = 0; s < 2; ++s) {
    lsum[s] += __shfl_xor(lsum[s], 16);
    lsum[s] += __shfl_xor(lsum[s], 32);
  }

  // epilogue: UNNORMALIZED partial O (bf16, [kv][bh][q][64]) + partial l (f32)
  bf16*  pO = pOb + (size_t)kv * (2048u * 16 * 64);
  float* pL = pLb + (size_t)kv * (2048u * 16);
  #pragma unroll
  for (int s = 0; s < 2; ++s) {
    if (lg == 0) pL[(size_t)bh * 2048 + qbase + s * 16 + lr] = lsum[s];
    #pragma unroll
    for (int j = 0; j < 4; ++j) {
      int gq = qbase + s * 16 + lg * 4 + j;
      #pragma unroll
      for (int n = 0; n < 4; ++n)
        pO[((size_t)bh * 2048 + gq) * 64 + n * 16 + lr] = (bf16)acc[s][n][j];
    }
  }
}

// ---------------- combine: ao[b][l][h*64+d] = sum_kv(pO)/sum_kv(l) ----------------
__global__ __launch_bounds__(256) void combine_kernel(
    const bf16* __restrict__ pOb, const float* __restrict__ pLb,
    bf16* __restrict__ ao) {
  int idx = blockIdx.x * 256 + threadIdx.x;
  int e8 = idx * 8;
  int row = e8 >> 9, col = e8 & 511;
  int b = row >> 11, lq = row & 2047, h = col >> 6, d0 = col & 63;
  size_t bhq = (size_t)(b * 8 + h) * 2048 + lq;
  size_t src = bhq * 64 + d0;
  float sum[8] = {0.f, 0.f, 0.f, 0.f, 0.f, 0.f, 0.f, 0.f};
  float lt = 0.f;
  #pragma unroll
  for (int p = 0; p < 8; ++p) {
    bf16x8 v = *(const bf16x8*)(pOb + (size_t)p * (2048u * 16 * 64) + src);
    #pragma unroll
    for (int i = 0; i < 8; ++i) sum[i] += (float)v[i];
    lt += pLb[(size_t)p * (2048u * 16) + bhq];
  }
  float inv = 1.f / lt;
  bf16x8 o;
  #pragma unroll
  for (int i = 0; i < 8; ++i) o[i] = (bf16)(sum[i] * inv);
  *(bf16x8*)(ao + e8) = o;
}

extern "C" void kernel_launch(void* const* d_in, const int* in_sizes, int n_in,
                              void* d_out, int out_size, void* d_ws, size_t ws_size,
                              hipStream_t stream) {
  const float* x  = (const float*)d_in[0];
  const float* wq = (const float*)d_in[1];
  const float* wk = (const float*)d_in[2];
  const float* wv = (const float*)d_in[3];
  const float* wo = (const float*)d_in[4];

  if (ws_size < (56u << 20)) return;  // need 56 MB scratch (harness provides ~256 MB)

  char* ws = (char*)d_ws;
  bf16* wqkv_t = (bf16*)(ws);                 // 1.5 MB (dead after gemm_qkv)
  bf16* wo_t   = (bf16*)(ws + (2 << 20));     // 0.5 MB (live until gemm_out)
  bf16* q_ws   = (bf16*)(ws + (4 << 20));     // 4 MB   [b][h][l][d]
  bf16* k_ws   = (bf16*)(ws + (8 << 20));     // 4 MB   [b][h][l][d]
  bf16* vt_ws  = (bf16*)(ws + (12 << 20));    // 4 MB   [b][h][d][l]
  bf16*  pOb   = (bf16*)(ws + (16 << 20));    // 32 MB  [kv=8][bh][q][64]
  float* pLb   = (float*)(ws + (48 << 20));   // 1 MB   [kv=8][bh][q]
  bf16*  ao    = (bf16*)(ws + (49 << 20));    // 4 MB   [4096][512]

  transpose_w_kernel<<<256, 256, 0, stream>>>(wq, wk, wv, wo, wqkv_t, wo_t);
  gemm_qkv_kernel<<<64 * 12, 256, 0, stream>>>(x, wqkv_t, q_ws, k_ws, vt_ws);
  attn_kernel<<<1024, 512, 0, stream>>>(q_ws, k_ws, vt_ws, pOb, pLb);
  combine_kernel<<<1024, 256, 0, stream>>>(pOb, pLb, ao);
  gemm_out_kernel<<<64 * 8, 256, 0, stream>>>(ao, wo_t, (float*)d_out, 4096, 512, 512);
}

// Round 26
// 68.478 us; speedup vs baseline: 1.8127x; 1.8127x over previous
//
#include <hip/hip_runtime.h>
#include <hip/hip_bf16.h>
#include <math.h>

typedef __bf16 bf16;
typedef __bf16 bf16x4 __attribute__((ext_vector_type(4)));
typedef __bf16 bf16x8 __attribute__((ext_vector_type(8)));
typedef float f32x4 __attribute__((ext_vector_type(4)));
typedef unsigned int uint32x4 __attribute__((ext_vector_type(4)));

#define AS1 __attribute__((address_space(1)))
#define AS3 __attribute__((address_space(3)))

__device__ __forceinline__ void gload_lds16(const void* g, void* l) {
  __builtin_amdgcn_global_load_lds((const AS1 void*)g, (AS3 void*)l, 16, 0, 0);
}

__device__ __forceinline__ unsigned packbf16(float a, float b) {
  bf16 x = (bf16)a, y = (bf16)b;
  unsigned short ux, uy;
  __builtin_memcpy(&ux, &x, 2);
  __builtin_memcpy(&uy, &y, 2);
  return (unsigned)ux | ((unsigned)uy << 16);
}

// ---------------- weight transpose: W[k][c] f32 -> Wt[c][k] bf16 ----------------
__global__ __launch_bounds__(256) void transpose_w_kernel(
    const float* __restrict__ wq, const float* __restrict__ wk,
    const float* __restrict__ wv, const float* __restrict__ wo,
    bf16* __restrict__ wqkv_t, bf16* __restrict__ wo_t) {
  __shared__ float t[64 * 65];
  int ct = blockIdx.x & 31, kt = blockIdx.x >> 5;
  int p = ct >> 3;                       // 0=wq 1=wk 2=wv 3=wo
  const float* src = (p == 0) ? wq : (p == 1) ? wk : (p == 2) ? wv : wo;
  int c0 = (ct & 7) * 64;
  int k0 = kt * 64;
  int tid = threadIdx.x;
  for (int i = 0; i < 16; ++i) {
    int idx = i * 256 + tid;
    int r = idx >> 6, c = idx & 63;
    t[r * 65 + c] = src[(size_t)(k0 + r) * 512 + c0 + c];
  }
  __syncthreads();
  for (int i = 0; i < 16; ++i) {
    int idx = i * 256 + tid;
    int cc = idx >> 6, kk = idx & 63;
    float v = t[kk * 65 + cc];
    int col = c0 + cc;
    if (p < 3) wqkv_t[(size_t)(p * 512 + col) * 512 + k0 + kk] = (bf16)v;
    else       wo_t[(size_t)col * 512 + k0 + kk] = (bf16)v;
  }
}

// ---------------- QKV GEMM with fused f32->bf16 cvt of x (A reg-staged) ----------------
// BM=64, BN=128; Q scaled by 0.125*log2(e) in epilogue.
__global__ __launch_bounds__(256) void gemm_qkv_kernel(
    const float* __restrict__ x, const bf16* __restrict__ Bt,
    bf16* __restrict__ qw, bf16* __restrict__ kw, bf16* __restrict__ vtw) {
  __shared__ bf16 ldsA[64 * 64];
  __shared__ bf16 ldsB[128 * 64];
  int tid = threadIdx.x;
  int wave = tid >> 6, l = tid & 63;
  int lr = l & 15, lg = l >> 4;
  int bm = blockIdx.x & 63, bn = blockIdx.x >> 6;
  int wr = wave >> 1, wc = wave & 1;

  f32x4 acc[2][4] = {};

  for (int k0 = 0; k0 < 512; k0 += 64) {
    #pragma unroll
    for (int i = 0; i < 4; ++i) {
      int off = i * 4096 + tid * 16;
      int r = off >> 7, cb = off & 127;
      gload_lds16((const char*)(Bt + (size_t)(bn * 128 + r) * 512 + k0) + cb,
                  (char*)ldsB + i * 4096 + wave * 1024);
    }
    #pragma unroll
    for (int c = 0; c < 4; ++c) {
      int idx = c * 256 + tid;            // 0..1023 float4-slots
      int r = idx >> 4, f4 = idx & 15;
      float4 v = *(const float4*)(x + (size_t)(bm * 64 + r) * 512 + k0 + f4 * 4);
      bf16x4 o;
      o[0] = (bf16)v.x; o[1] = (bf16)v.y; o[2] = (bf16)v.z; o[3] = (bf16)v.w;
      *(bf16x4*)(ldsA + r * 64 + f4 * 4) = o;
    }
    __syncthreads();
    #pragma unroll
    for (int ks = 0; ks < 2; ++ks) {
      bf16x8 af[2], bfr[4];
      #pragma unroll
      for (int m = 0; m < 2; ++m)
        af[m] = *(const bf16x8*)(ldsA + (wr * 32 + m * 16 + lr) * 64 + ks * 32 + lg * 8);
      #pragma unroll
      for (int n = 0; n < 4; ++n)
        bfr[n] = *(const bf16x8*)(ldsB + (wc * 64 + n * 16 + lr) * 64 + ks * 32 + lg * 8);
      #pragma unroll
      for (int m = 0; m < 2; ++m)
        #pragma unroll
        for (int n = 0; n < 4; ++n)
          acc[m][n] = __builtin_amdgcn_mfma_f32_16x16x32_bf16(af[m], bfr[n], acc[m][n], 0, 0, 0);
    }
    __syncthreads();
  }

  #pragma unroll
  for (int m = 0; m < 2; ++m)
    #pragma unroll
    for (int n = 0; n < 4; ++n)
      #pragma unroll
      for (int j = 0; j < 4; ++j) {
        float v = acc[m][n][j];
        int row = bm * 64 + wr * 32 + m * 16 + lg * 4 + j;
        int col = bn * 128 + wc * 64 + n * 16 + lr;
        int part = col >> 9, cp = col & 511;
        int h = cp >> 6, d = cp & 63;
        int b = row >> 11, lq = row & 2047;
        size_t bh = (size_t)(b * 8 + h);
        if (part == 0)      qw[(bh * 2048 + lq) * 64 + d] = (bf16)(v * 0.18033688f);
        else if (part == 1) kw[(bh * 2048 + lq) * 64 + d] = (bf16)v;
        else                vtw[(bh * 64 + d) * 2048 + lq] = (bf16)v;
      }
}

// ---------------- output GEMM: C[M][N] = A[M][K] * Bt[N][K]^T, f32 out ----------------
__global__ __launch_bounds__(256) void gemm_out_kernel(
    const bf16* __restrict__ A, const bf16* __restrict__ Bt,
    float* __restrict__ Cf, int M, int N, int K) {
  __shared__ bf16 ldsA[64 * 64];
  __shared__ bf16 ldsB[64 * 64];
  int tid = threadIdx.x;
  int wave = tid >> 6, l = tid & 63;
  int lr = l & 15, lg = l >> 4;
  int nbm = M >> 6;
  int bm = blockIdx.x % nbm, bn = blockIdx.x / nbm;
  int wr = wave >> 1, wc = wave & 1;

  f32x4 acc[2][2] = {};

  for (int k0 = 0; k0 < K; k0 += 64) {
    #pragma unroll
    for (int i = 0; i < 2; ++i) {
      int off = i * 4096 + tid * 16;
      int r = off >> 7, cb = off & 127;
      gload_lds16((const char*)(A + (size_t)(bm * 64 + r) * K + k0) + cb,
                  (char*)ldsA + i * 4096 + wave * 1024);
      gload_lds16((const char*)(Bt + (size_t)(bn * 64 + r) * K + k0) + cb,
                  (char*)ldsB + i * 4096 + wave * 1024);
    }
    __syncthreads();
    #pragma unroll
    for (int ks = 0; ks < 2; ++ks) {
      bf16x8 af[2], bfr[2];
      #pragma unroll
      for (int m = 0; m < 2; ++m)
        af[m] = *(const bf16x8*)(ldsA + (wr * 32 + m * 16 + lr) * 64 + ks * 32 + lg * 8);
      #pragma unroll
      for (int n = 0; n < 2; ++n)
        bfr[n] = *(const bf16x8*)(ldsB + (wc * 32 + n * 16 + lr) * 64 + ks * 32 + lg * 8);
      #pragma unroll
      for (int m = 0; m < 2; ++m)
        #pragma unroll
        for (int n = 0; n < 2; ++n)
          acc[m][n] = __builtin_amdgcn_mfma_f32_16x16x32_bf16(af[m], bfr[n], acc[m][n], 0, 0, 0);
    }
    __syncthreads();
  }

  #pragma unroll
  for (int m = 0; m < 2; ++m)
    #pragma unroll
    for (int n = 0; n < 2; ++n)
      #pragma unroll
      for (int j = 0; j < 4; ++j) {
        int row = bm * 64 + wr * 32 + m * 16 + lg * 4 + j;
        int col = bn * 64 + wc * 32 + n * 16 + lr;
        Cf[(size_t)row * N + col] = acc[m][n][j];
      }
}

// ---------------- attention (r16/r19/r22 version): LDS-staged, vmcnt(2) 2-buffer pipeline ----------------
// 8 waves x 32 q-rows; grid 512 = 2 blocks/CU = 16 waves/CU. Swapped QK^T with
// remapped K-rows keeps P in registers. Measured optimum of 7 structural
// variants; every perturbation (direct-L2, 4-buffer ring, kv x8 at two
// launch-bounds settings, counted-vmcnt-only, 8-wave q-tile) regressed or null.
__global__ __launch_bounds__(512, 4) void attn_kernel(
    const bf16* __restrict__ qw, const bf16* __restrict__ kw,
    const bf16* __restrict__ vtw,
    bf16* __restrict__ pO0, bf16* __restrict__ pO1,
    bf16* __restrict__ pO2, bf16* __restrict__ pO3,
    float* __restrict__ pL0, float* __restrict__ pL1,
    float* __restrict__ pL2, float* __restrict__ pL3) {
  __shared__ bf16 ldsK[2][64 * 64];
  __shared__ bf16 ldsV[2][64 * 64];   // [d][s] layout (V^T tile)

  // bijective XCD swizzle: 512 blocks -> each XCD gets 64 consecutive = 2 bh
  int swzb = ((blockIdx.x & 7) << 6) | (blockIdx.x >> 3);
  int bh = swzb >> 5, qblk = (swzb >> 2) & 7, kv = swzb & 3;

  int tid = threadIdx.x, wave = tid >> 6, l = tid & 63;
  int lr = l & 15, lg = l >> 4;
  const bf16* Q  = qw  + (size_t)bh * 2048 * 64;
  const bf16* Kp = kw  + (size_t)bh * 2048 * 64;
  const bf16* Vt = vtw + (size_t)bh * 64 * 2048;
  int qbase = qblk * 256 + wave * 32;
  int td = qblk * 4 + (wave >> 1);     // k-tile containing this wave's diagonal
  int qoff = (wave & 1) * 32;          // wave's offset within tile td

  // Q fragments (pre-scaled by 0.125*log2e in QKV epilogue): 2 subtiles x 2 ks
  bf16x8 qf[2][2];
  #pragma unroll
  for (int s = 0; s < 2; ++s)
    #pragma unroll
    for (int ks = 0; ks < 2; ++ks)
      qf[s][ks] = *(const bf16x8*)(Q + (size_t)(qbase + s * 16 + lr) * 64 + ks * 32 + lg * 8);

  // staging: 512 threads cover one 64x128B tile per gload; SWZ(r)=((r&3)|((r>>3&1)<<2))<<4
  int rowT = tid >> 3;
  int colT = (tid & 7) * 16;
  int swc = colT ^ ((((rowT & 3) | (((rowT >> 3) & 1) << 2))) << 4);

  // read-side xor constants (SWZ of the row being read; n-independent)
  int kxor = (((lr & 3) | (((lr >> 2) & 1) << 2)) << 4);
  int vxor = (((lr & 3) | (((lr >> 3) & 1) << 2)) << 4);

  f32x4 acc[2][4] = {};
  float lsum[2] = {0.f, 0.f};

  auto stage = [&](int buf, int t) {
    gload_lds16((const char*)Kp + (size_t)t * 8192 + rowT * 128 + swc,
                (char*)ldsK[buf] + wave * 1024);
    gload_lds16((const char*)Vt + (size_t)t * 128 + (size_t)rowT * 4096 + swc,
                (char*)ldsV[buf] + wave * 1024);
  };

  int t0 = kv * 8;
  stage(0, t0);

  for (int tt = 0; tt < 8; ++tt) {
    int t = t0 + tt;
    int buf = tt & 1;
    if (tt < 7) {
      stage(buf ^ 1, t + 1);                           // next tile stays in flight
      asm volatile("s_waitcnt vmcnt(2)" ::: "memory"); // current-buf loads done
    } else {
      asm volatile("s_waitcnt vmcnt(0)" ::: "memory");
    }
    __builtin_amdgcn_s_barrier();
    __builtin_amdgcn_sched_barrier(0);

    // swapped QK^T with remapped K-rows: ps[s][n] lane(lr,lg) reg j =
    //   P[k=(n>>1)*32+lg*8+(n&1)*4+j][q=qbase+s*16+lr]
    f32x4 ps[2][4] = {};
    __builtin_amdgcn_s_setprio(1);
    #pragma unroll
    for (int ks = 0; ks < 2; ++ks)
      #pragma unroll
      for (int n = 0; n < 4; ++n) {
        int mrow = ((n >> 1) << 5) + ((lr >> 2) << 3) + ((n & 1) << 2) + (lr & 3);
        bf16x8 kf = *(const bf16x8*)((const char*)ldsK[buf] + mrow * 128 +
                                     ((ks * 64 + lg * 16) ^ kxor));
        #pragma unroll
        for (int s = 0; s < 2; ++s)
          ps[s][n] = __builtin_amdgcn_mfma_f32_16x16x32_bf16(kf, qf[s][ks], ps[s][n], 0, 0, 0);
      }
    __builtin_amdgcn_s_setprio(0);

    // diagonal mask: k_local == q_local within this wave's diagonal tile
    if (t == td) {
      #pragma unroll
      for (int s = 0; s < 2; ++s)
        #pragma unroll
        for (int n = 0; n < 4; ++n)
          #pragma unroll
          for (int j = 0; j < 4; ++j)
            if (((n >> 1) * 32 + lg * 8 + (n & 1) * 4 + j) == qoff + s * 16 + lr)
              ps[s][n][j] = -INFINITY;
    }

    // fixed-max softmax (bare v_exp_f32) + in-register P->bf16 A-fragment assembly
    bf16x8 pf[2][2];
    #pragma unroll
    for (int s = 0; s < 2; ++s) {
      unsigned u[4][2];
      #pragma unroll
      for (int n = 0; n < 4; ++n) {
        float p0 = __builtin_amdgcn_exp2f(ps[s][n][0]);
        float p1 = __builtin_amdgcn_exp2f(ps[s][n][1]);
        float p2 = __builtin_amdgcn_exp2f(ps[s][n][2]);
        float p3 = __builtin_amdgcn_exp2f(ps[s][n][3]);
        lsum[s] += (p0 + p1) + (p2 + p3);
        u[n][0] = packbf16(p0, p1);
        u[n][1] = packbf16(p2, p3);
      }
      uint32x4 w0 = {u[0][0], u[0][1], u[1][0], u[1][1]};
      uint32x4 w1 = {u[2][0], u[2][1], u[3][0], u[3][1]};
      pf[s][0] = __builtin_bit_cast(bf16x8, w0);
      pf[s][1] = __builtin_bit_cast(bf16x8, w1);
    }

    // O += P V : vf shared across both subtiles
    __builtin_amdgcn_s_setprio(1);
    #pragma unroll
    for (int ks = 0; ks < 2; ++ks)
      #pragma unroll
      for (int n = 0; n < 4; ++n) {
        int vrow = n * 16 + lr;
        bf16x8 vf = *(const bf16x8*)((const char*)ldsV[buf] + vrow * 128 +
                                     ((ks * 64 + lg * 16) ^ vxor));
        #pragma unroll
        for (int s = 0; s < 2; ++s)
          acc[s][n] = __builtin_amdgcn_mfma_f32_16x16x32_bf16(pf[s][ks], vf, acc[s][n], 0, 0, 0);
      }
    __builtin_amdgcn_s_setprio(0);
    __builtin_amdgcn_s_barrier();          // release buf before next iter's stage
  }

  // lsum: reduce across the 4 lg-groups sharing the same q (=lr)
  #pragma unroll
  for (int s = 0; s < 2; ++s) {
    lsum[s] += __shfl_xor(lsum[s], 16);
    lsum[s] += __shfl_xor(lsum[s], 32);
  }

  // epilogue: UNNORMALIZED partial O (bf16, [bh][q][64]) + partial l (f32)
  bf16*  pO = (kv == 0) ? pO0 : (kv == 1) ? pO1 : (kv == 2) ? pO2 : pO3;
  float* pL = (kv == 0) ? pL0 : (kv == 1) ? pL1 : (kv == 2) ? pL2 : pL3;
  #pragma unroll
  for (int s = 0; s < 2; ++s) {
    if (lg == 0) pL[(size_t)bh * 2048 + qbase + s * 16 + lr] = lsum[s];
    #pragma unroll
    for (int j = 0; j < 4; ++j) {
      int gq = qbase + s * 16 + lg * 4 + j;
      #pragma unroll
      for (int n = 0; n < 4; ++n)
        pO[((size_t)bh * 2048 + gq) * 64 + n * 16 + lr] = (bf16)acc[s][n][j];
    }
  }
}

// ---------------- combine: ao[b][l][h*64+d] = sum(pO)/sum(l) ----------------
__global__ __launch_bounds__(256) void combine_kernel(
    const bf16* __restrict__ pO0, const bf16* __restrict__ pO1,
    const bf16* __restrict__ pO2, const bf16* __restrict__ pO3,
    const float* __restrict__ pL0, const float* __restrict__ pL1,
    const float* __restrict__ pL2, const float* __restrict__ pL3,
    bf16* __restrict__ ao) {
  int idx = blockIdx.x * 256 + threadIdx.x;
  int e8 = idx * 8;
  int row = e8 >> 9, col = e8 & 511;
  int b = row >> 11, lq = row & 2047, h = col >> 6, d0 = col & 63;
  size_t bhq = (size_t)(b * 8 + h) * 2048 + lq;
  size_t src = bhq * 64 + d0;
  bf16x8 v0 = *(const bf16x8*)(pO0 + src);
  bf16x8 v1 = *(const bf16x8*)(pO1 + src);
  bf16x8 v2 = *(const bf16x8*)(pO2 + src);
  bf16x8 v3 = *(const bf16x8*)(pO3 + src);
  float inv = 1.f / (pL0[bhq] + pL1[bhq] + pL2[bhq] + pL3[bhq]);
  bf16x8 o;
  #pragma unroll
  for (int i = 0; i < 8; ++i)
    o[i] = (bf16)(((float)v0[i] + (float)v1[i] + (float)v2[i] + (float)v3[i]) * inv);
  *(bf16x8*)(ao + e8) = o;
}

extern "C" void kernel_launch(void* const* d_in, const int* in_sizes, int n_in,
                              void* d_out, int out_size, void* d_ws, size_t ws_size,
                              hipStream_t stream) {
  const float* x  = (const float*)d_in[0];
  const float* wq = (const float*)d_in[1];
  const float* wk = (const float*)d_in[2];
  const float* wv = (const float*)d_in[3];
  const float* wo = (const float*)d_in[4];

  if (ws_size < (32u << 20)) return;  // need 32 MB scratch

  char* ws = (char*)d_ws;
  bf16* wqkv_t = (bf16*)(ws + (4 << 20));     // 1.5 MB (dead after gemm_qkv)
  bf16* wo_t   = (bf16*)(ws + (6 << 20));     // 0.5 MB (live until gemm_out)
  bf16* q_ws   = (bf16*)(ws + (8 << 20));     // 4 MB   [b][h][l][d]
  bf16* k_ws   = (bf16*)(ws + (12 << 20));    // 4 MB   [b][h][l][d]
  bf16* vt_ws  = (bf16*)(ws + (16 << 20));    // 4 MB   [b][h][d][l]
  // attn partials overlay dead regions:
  bf16*  pO0 = (bf16*)(ws);                   // 4 MB (ws+0 unused by projections)
  float* pL0 = (float*)(ws + (4 << 20));
  float* pL1 = (float*)(ws + (4 << 20) + (128 << 10));
  float* pL2 = (float*)(ws + (4 << 20) + (256 << 10));
  float* pL3 = (float*)(ws + (4 << 20) + (384 << 10));
  bf16*  pO1 = (bf16*)(ws + (20 << 20));      // 4 MB
  bf16*  pO2 = (bf16*)(ws + (24 << 20));      // 4 MB
  bf16*  pO3 = (bf16*)(ws + (28 << 20));      // 4 MB
  // combine output overlays q_ws (dead after attn)
  bf16*  ao  = (bf16*)(ws + (8 << 20));       // 4 MB [4096][512]

  transpose_w_kernel<<<256, 256, 0, stream>>>(wq, wk, wv, wo, wqkv_t, wo_t);
  gemm_qkv_kernel<<<64 * 12, 256, 0, stream>>>(x, wqkv_t, q_ws, k_ws, vt_ws);
  attn_kernel<<<512, 512, 0, stream>>>(q_ws, k_ws, vt_ws, pO0, pO1, pO2, pO3,
                                       pL0, pL1, pL2, pL3);
  combine_kernel<<<1024, 256, 0, stream>>>(pO0, pO1, pO2, pO3, pL0, pL1, pL2, pL3, ao);
  gemm_out_kernel<<<64 * 8, 256, 0, stream>>>(ao, wo_t, (float*)d_out, 4096, 512, 512);
}